// Round 3
// baseline (2341.797 us; speedup 1.0000x reference)
//
#include <hip/hip_runtime.h>
#include <math.h>

#define N_NODES 100000
#define N_EDGES 3200000
#define N_GRAPHS 512
#define D_FEAT 128
#define F_HID 32

#define RPB 128                 // rows per bucket (row >> 7)
#define NB 782                  // ceil(100000/128)
#define CHUNK 8192              // edges per multisplit block
#define NCHUNK ((N_EDGES + CHUNK - 1) / CHUNK)   // 391

// ---------------- GEMM1: x[N,128] @ W[128,32] -> out[N,32] ----------------
__global__ void gemm128x32(const float* __restrict__ x, const float* __restrict__ W,
                           float* __restrict__ out, int n_nodes) {
    __shared__ float Ws[128 * 32];
    for (int i = threadIdx.x; i < 128 * 32; i += 256) Ws[i] = W[i];
    __syncthreads();
    const int fg = threadIdx.x & 7;
    const int nl = threadIdx.x >> 3;
    const int node = blockIdx.x * 32 + nl;
    if (node >= n_nodes) return;
    const float4* x4 = (const float4*)(x + (size_t)node * 128);
    const float4* Ws4 = (const float4*)Ws;
    float4 acc = make_float4(0.f, 0.f, 0.f, 0.f);
    for (int kk = 0; kk < 32; ++kk) {
        float4 xv = x4[kk];
        int k = kk * 4;
        float4 w0 = Ws4[(k + 0) * 8 + fg];
        float4 w1 = Ws4[(k + 1) * 8 + fg];
        float4 w2 = Ws4[(k + 2) * 8 + fg];
        float4 w3 = Ws4[(k + 3) * 8 + fg];
        acc.x += xv.x * w0.x + xv.y * w1.x + xv.z * w2.x + xv.w * w3.x;
        acc.y += xv.x * w0.y + xv.y * w1.y + xv.z * w2.y + xv.w * w3.y;
        acc.z += xv.x * w0.z + xv.y * w1.z + xv.z * w2.z + xv.w * w3.z;
        acc.w += xv.x * w0.w + xv.y * w1.w + xv.z * w2.w + xv.w * w3.w;
    }
    ((float4*)(out + (size_t)node * 32))[fg] = acc;
}

// ---------------- GEMM: h[N,32] @ W[32,32] -> out[N,32] ----------------
__global__ void gemm32x32(const float* __restrict__ h, const float* __restrict__ W,
                          float* __restrict__ out, int n_nodes) {
    __shared__ float Ws[32 * 32];
    for (int i = threadIdx.x; i < 32 * 32; i += 256) Ws[i] = W[i];
    __syncthreads();
    const int fg = threadIdx.x & 7;
    const int nl = threadIdx.x >> 3;
    const int node = blockIdx.x * 32 + nl;
    if (node >= n_nodes) return;
    const float4* h4 = (const float4*)(h + (size_t)node * 32);
    const float4* Ws4 = (const float4*)Ws;
    float4 acc = make_float4(0.f, 0.f, 0.f, 0.f);
    for (int kk = 0; kk < 8; ++kk) {
        float4 hv = h4[kk];
        int k = kk * 4;
        float4 w0 = Ws4[(k + 0) * 8 + fg];
        float4 w1 = Ws4[(k + 1) * 8 + fg];
        float4 w2 = Ws4[(k + 2) * 8 + fg];
        float4 w3 = Ws4[(k + 3) * 8 + fg];
        acc.x += hv.x * w0.x + hv.y * w1.x + hv.z * w2.x + hv.w * w3.x;
        acc.y += hv.x * w0.y + hv.y * w1.y + hv.z * w2.y + hv.w * w3.y;
        acc.z += hv.x * w0.z + hv.y * w1.z + hv.z * w2.z + hv.w * w3.z;
        acc.w += hv.x * w0.w + hv.y * w1.w + hv.z * w2.w + hv.w * w3.w;
    }
    ((float4*)(out + (size_t)node * 32))[fg] = acc;
}

// ================= bucket multisplit =================
__global__ void bucket_hist(const int* __restrict__ row, int* __restrict__ cnt, int n_edges) {
    __shared__ int h[NB];
    for (int i = threadIdx.x; i < NB; i += 256) h[i] = 0;
    __syncthreads();
    const int base = blockIdx.x * CHUNK;
    for (int i = threadIdx.x; i < CHUNK; i += 256) {
        int e = base + i;
        if (e < n_edges) atomicAdd(&h[row[e] >> 7], 1);
    }
    __syncthreads();
    for (int i = threadIdx.x; i < NB; i += 256) {
        int c = h[i];
        if (c) atomicAdd(&cnt[i], c);
    }
}

// single block of 1024: exclusive scan of cnt[NB] -> bbase[NB+1]; cursor init
__global__ void scan_nb(const int* __restrict__ cnt, int* __restrict__ bbase,
                        int* __restrict__ cursor) {
    __shared__ int s[1024];
    const int t = threadIdx.x;
    int v = (t < NB) ? cnt[t] : 0;
    s[t] = v;
    __syncthreads();
    for (int off = 1; off < 1024; off <<= 1) {
        int add = (t >= off) ? s[t - off] : 0;
        __syncthreads();
        s[t] += add;
        __syncthreads();
    }
    if (t < NB) {
        int excl = s[t] - v;
        bbase[t] = excl;
        cursor[t] = excl;
    }
    if (t == NB - 1) bbase[NB] = s[t];
}

__global__ void bucket_scatter(const int* __restrict__ row, const int* __restrict__ col,
                               const float* __restrict__ w, int* __restrict__ cursor,
                               uint2* __restrict__ rec, int n_edges) {
    __shared__ int h[NB];      // hist, then local cursor
    __shared__ int lbase[NB];  // this block's reserved base per bucket
    for (int i = threadIdx.x; i < NB; i += 256) h[i] = 0;
    __syncthreads();
    const int base = blockIdx.x * CHUNK;
    // pass 1: local histogram
    for (int i = threadIdx.x; i < CHUNK; i += 256) {
        int e = base + i;
        if (e < n_edges) atomicAdd(&h[row[e] >> 7], 1);
    }
    __syncthreads();
    // reserve global ranges
    for (int i = threadIdx.x; i < NB; i += 256) {
        int c = h[i];
        lbase[i] = c ? atomicAdd(&cursor[i], c) : 0;
    }
    __syncthreads();
    for (int i = threadIdx.x; i < NB; i += 256) h[i] = 0;
    __syncthreads();
    // pass 2: place records
    for (int i = threadIdx.x; i < CHUNK; i += 256) {
        int e = base + i;
        if (e < n_edges) {
            int r = row[e];
            int b = r >> 7;
            int pos = lbase[b] + atomicAdd(&h[b], 1);
            unsigned packed = ((unsigned)(r & 127) << 17) | (unsigned)col[e];
            rec[pos] = make_uint2(packed, __float_as_uint(w[e]));
        }
    }
}

// ================= SPMM per bucket (LDS accumulate) + bias + ELU =================
// block = 256: 8 edge-groups x 32 feat lanes. acc in LDS (128 rows x 32 feats).
__global__ void spmm_bucket(const int* __restrict__ bbase, const uint2* __restrict__ rec,
                            const float* __restrict__ hin, const float* __restrict__ bias,
                            float* __restrict__ out, int n_nodes) {
    __shared__ float acc[RPB * 32];
    const int t = threadIdx.x;
    for (int i = t; i < RPB * 32; i += 256) acc[i] = 0.f;
    __syncthreads();
    const int b = blockIdx.x;
    const int s = bbase[b], e = bbase[b + 1];
    const int f = t & 31;
    const int g = t >> 5;     // 0..7
    for (int i = s + g; i < e; i += 32) {
        const int i1 = i + 8, i2 = i + 16, i3 = i + 24;
        uint2 r0 = rec[i];
        uint2 r1 = (i1 < e) ? rec[i1] : make_uint2(0u, 0u);
        uint2 r2 = (i2 < e) ? rec[i2] : make_uint2(0u, 0u);
        uint2 r3 = (i3 < e) ? rec[i3] : make_uint2(0u, 0u);
        float h0 = hin[(size_t)(r0.x & 0x1FFFF) * 32 + f];
        float h1 = hin[(size_t)(r1.x & 0x1FFFF) * 32 + f];
        float h2 = hin[(size_t)(r2.x & 0x1FFFF) * 32 + f];
        float h3 = hin[(size_t)(r3.x & 0x1FFFF) * 32 + f];
        atomicAdd(&acc[(r0.x >> 17) * 32 + f], __uint_as_float(r0.y) * h0);
        if (i1 < e) atomicAdd(&acc[(r1.x >> 17) * 32 + f], __uint_as_float(r1.y) * h1);
        if (i2 < e) atomicAdd(&acc[(r2.x >> 17) * 32 + f], __uint_as_float(r2.y) * h2);
        if (i3 < e) atomicAdd(&acc[(r3.x >> 17) * 32 + f], __uint_as_float(r3.y) * h3);
    }
    __syncthreads();
    const int row0 = b * RPB;
    for (int i = t; i < RPB * 32; i += 256) {
        int r = row0 + (i >> 5);
        if (r < n_nodes) {
            float v = acc[i] + bias[i & 31];
            out[(size_t)r * 32 + (i & 31)] = v > 0.f ? v : (expf(v) - 1.f);
        }
    }
}

// ================= pool: sorted seg run-accumulation =================
__global__ void pool_seg(const float* __restrict__ h, const int* __restrict__ seg,
                         float* __restrict__ g, int n_nodes) {
    const int t = threadIdx.x;
    const int f = t & 31;
    const int sub = t >> 5;
    const int base = blockIdx.x * 512;
    float run = 0.f;
    int cur = -1;
    for (int i = 0; i < 64; ++i) {
        int node = base + sub + i * 8;
        if (node >= n_nodes) break;
        int sg = seg[node];
        if (sg != cur) {
            if (cur >= 0) atomicAdd(&g[(size_t)cur * 32 + f], run);
            cur = sg;
            run = 0.f;
        }
        run += h[(size_t)node * 32 + f];
    }
    if (cur >= 0) atomicAdd(&g[(size_t)cur * 32 + f], run);
}

// ================= MLP head =================
__global__ void head_mlp(const float* __restrict__ g,
                         const float* __restrict__ Wd1, const float* __restrict__ bd1,
                         const float* __restrict__ Wd2, const float* __restrict__ bd2,
                         const float* __restrict__ Wd3, const float* __restrict__ bd3,
                         float* __restrict__ out) {
    __shared__ float gr[32];
    __shared__ float s1[64];
    __shared__ float s2[32];
    const int gid = blockIdx.x;
    const int t = threadIdx.x;
    if (t < 32) gr[t] = g[(size_t)gid * 32 + t];
    __syncthreads();
    float a = bd1[t];
    for (int k = 0; k < 32; ++k) a += gr[k] * Wd1[k * 64 + t];
    s1[t] = fmaxf(a, 0.f);
    __syncthreads();
    if (t < 32) {
        float a2 = bd2[t];
        for (int k = 0; k < 64; ++k) a2 += s1[k] * Wd2[k * 32 + t];
        s2[t] = fmaxf(a2, 0.f);
    }
    __syncthreads();
    if (t == 0) {
        float a3 = bd3[0];
        for (int k = 0; k < 32; ++k) a3 += s2[k] * Wd3[k];
        out[gid] = 1.f / (1.f + expf(-a3));
    }
}

extern "C" void kernel_launch(void* const* d_in, const int* in_sizes, int n_in,
                              void* d_out, int out_size, void* d_ws, size_t ws_size,
                              hipStream_t stream) {
    const float* x   = (const float*)d_in[0];
    const int*   ei  = (const int*)d_in[1];
    const float* ew  = (const float*)d_in[2];
    const int*   seg = (const int*)d_in[3];
    const float* W1  = (const float*)d_in[4];
    const float* b1  = (const float*)d_in[5];
    const float* W2  = (const float*)d_in[6];
    const float* b2  = (const float*)d_in[7];
    const float* W3  = (const float*)d_in[8];
    const float* b3  = (const float*)d_in[9];
    const float* Wd1 = (const float*)d_in[10];
    const float* bd1 = (const float*)d_in[11];
    const float* Wd2 = (const float*)d_in[12];
    const float* bd2 = (const float*)d_in[13];
    const float* Wd3 = (const float*)d_in[14];
    const float* bd3 = (const float*)d_in[15];
    float* out = (float*)d_out;

    const int* rowp = ei;
    const int* colp = ei + N_EDGES;

    const size_t NF = (size_t)N_NODES * F_HID;
    float* B0     = (float*)d_ws;            // projected h
    float* B2     = B0 + NF;                 // activated h
    uint2* rec    = (uint2*)(B2 + NF);       // [E] packed (rowlocal|col, w)
    int*   cnt    = (int*)(rec + N_EDGES);   // [NB]
    int*   bbase  = cnt + NB;                // [NB+1]
    int*   cursor = bbase + NB + 1;          // [NB]
    float* G      = (float*)(cursor + NB);   // [512,32]

    const int gemm_grid = (N_NODES + 31) / 32;
    const int pool_grid = (N_NODES + 511) / 512;

    // ---- bucket multisplit (once per call) ----
    hipMemsetAsync(cnt, 0, NB * sizeof(int), stream);
    bucket_hist<<<NCHUNK, 256, 0, stream>>>(rowp, cnt, N_EDGES);
    scan_nb<<<1, 1024, 0, stream>>>(cnt, bbase, cursor);
    bucket_scatter<<<NCHUNK, 256, 0, stream>>>(rowp, colp, ew, cursor, rec, N_EDGES);

    // ---- layer 1 ----
    gemm128x32<<<gemm_grid, 256, 0, stream>>>(x, W1, B0, N_NODES);
    spmm_bucket<<<NB, 256, 0, stream>>>(bbase, rec, B0, b1, B2, N_NODES);

    // ---- layer 2 ----
    gemm32x32<<<gemm_grid, 256, 0, stream>>>(B2, W2, B0, N_NODES);
    spmm_bucket<<<NB, 256, 0, stream>>>(bbase, rec, B0, b2, B2, N_NODES);

    // ---- layer 3 ----
    gemm32x32<<<gemm_grid, 256, 0, stream>>>(B2, W3, B0, N_NODES);
    spmm_bucket<<<NB, 256, 0, stream>>>(bbase, rec, B0, b3, B2, N_NODES);

    // ---- pool + head ----
    hipMemsetAsync(G, 0, (size_t)N_GRAPHS * F_HID * sizeof(float), stream);
    pool_seg<<<pool_grid, 256, 0, stream>>>(B2, seg, G, N_NODES);
    head_mlp<<<N_GRAPHS, 64, 0, stream>>>(G, Wd1, bd1, Wd2, bd2, Wd3, bd3, out);
}

// Round 4
// 524.559 us; speedup vs baseline: 4.4643x; 4.4643x over previous
//
#include <hip/hip_runtime.h>
#include <math.h>

#define N_NODES 100000
#define N_EDGES 3200000
#define N_GRAPHS 512
#define D_FEAT 128
#define F_HID 32

#define RPB 128                 // rows per bucket (row >> 7)
#define NB 782                  // ceil(100000/128)
#define CHUNK 8192              // edges per multisplit block
#define NCHUNK ((N_EDGES + CHUNK - 1) / CHUNK)   // 391

// ---------------- GEMM1: x[N,128] @ W[128,32] -> out[N,32] ----------------
__global__ void gemm128x32(const float* __restrict__ x, const float* __restrict__ W,
                           float* __restrict__ out, int n_nodes) {
    __shared__ float Ws[128 * 32];
    for (int i = threadIdx.x; i < 128 * 32; i += 256) Ws[i] = W[i];
    __syncthreads();
    const int fg = threadIdx.x & 7;
    const int nl = threadIdx.x >> 3;
    const int node = blockIdx.x * 32 + nl;
    if (node >= n_nodes) return;
    const float4* x4 = (const float4*)(x + (size_t)node * 128);
    const float4* Ws4 = (const float4*)Ws;
    float4 acc = make_float4(0.f, 0.f, 0.f, 0.f);
    for (int kk = 0; kk < 32; ++kk) {
        float4 xv = x4[kk];
        int k = kk * 4;
        float4 w0 = Ws4[(k + 0) * 8 + fg];
        float4 w1 = Ws4[(k + 1) * 8 + fg];
        float4 w2 = Ws4[(k + 2) * 8 + fg];
        float4 w3 = Ws4[(k + 3) * 8 + fg];
        acc.x += xv.x * w0.x + xv.y * w1.x + xv.z * w2.x + xv.w * w3.x;
        acc.y += xv.x * w0.y + xv.y * w1.y + xv.z * w2.y + xv.w * w3.y;
        acc.z += xv.x * w0.z + xv.y * w1.z + xv.z * w2.z + xv.w * w3.z;
        acc.w += xv.x * w0.w + xv.y * w1.w + xv.z * w2.w + xv.w * w3.w;
    }
    ((float4*)(out + (size_t)node * 32))[fg] = acc;
}

// ---------------- GEMM: h[N,32] @ W[32,32] -> out[N,32] ----------------
__global__ void gemm32x32(const float* __restrict__ h, const float* __restrict__ W,
                          float* __restrict__ out, int n_nodes) {
    __shared__ float Ws[32 * 32];
    for (int i = threadIdx.x; i < 32 * 32; i += 256) Ws[i] = W[i];
    __syncthreads();
    const int fg = threadIdx.x & 7;
    const int nl = threadIdx.x >> 3;
    const int node = blockIdx.x * 32 + nl;
    if (node >= n_nodes) return;
    const float4* h4 = (const float4*)(h + (size_t)node * 32);
    const float4* Ws4 = (const float4*)Ws;
    float4 acc = make_float4(0.f, 0.f, 0.f, 0.f);
    for (int kk = 0; kk < 8; ++kk) {
        float4 hv = h4[kk];
        int k = kk * 4;
        float4 w0 = Ws4[(k + 0) * 8 + fg];
        float4 w1 = Ws4[(k + 1) * 8 + fg];
        float4 w2 = Ws4[(k + 2) * 8 + fg];
        float4 w3 = Ws4[(k + 3) * 8 + fg];
        acc.x += hv.x * w0.x + hv.y * w1.x + hv.z * w2.x + hv.w * w3.x;
        acc.y += hv.x * w0.y + hv.y * w1.y + hv.z * w2.y + hv.w * w3.y;
        acc.z += hv.x * w0.z + hv.y * w1.z + hv.z * w2.z + hv.w * w3.z;
        acc.w += hv.x * w0.w + hv.y * w1.w + hv.z * w2.w + hv.w * w3.w;
    }
    ((float4*)(out + (size_t)node * 32))[fg] = acc;
}

// ================= stage 1: bucket multisplit =================
__global__ void bucket_hist(const int* __restrict__ row, int* __restrict__ cnt, int n_edges) {
    __shared__ int h[NB];
    for (int i = threadIdx.x; i < NB; i += 256) h[i] = 0;
    __syncthreads();
    const int base = blockIdx.x * CHUNK;
    for (int i = threadIdx.x; i < CHUNK; i += 256) {
        int e = base + i;
        if (e < n_edges) atomicAdd(&h[row[e] >> 7], 1);
    }
    __syncthreads();
    for (int i = threadIdx.x; i < NB; i += 256) {
        int c = h[i];
        if (c) atomicAdd(&cnt[i], c);
    }
}

// single block of 1024: exclusive scan of cnt[NB] -> bbase[NB+1]; cursor init
__global__ void scan_nb(const int* __restrict__ cnt, int* __restrict__ bbase,
                        int* __restrict__ cursor) {
    __shared__ int s[1024];
    const int t = threadIdx.x;
    int v = (t < NB) ? cnt[t] : 0;
    s[t] = v;
    __syncthreads();
    for (int off = 1; off < 1024; off <<= 1) {
        int add = (t >= off) ? s[t - off] : 0;
        __syncthreads();
        s[t] += add;
        __syncthreads();
    }
    if (t < NB) {
        int excl = s[t] - v;
        bbase[t] = excl;
        cursor[t] = excl;
    }
    if (t == NB - 1) bbase[NB] = s[t];
}

__global__ void bucket_scatter(const int* __restrict__ row, const int* __restrict__ col,
                               const float* __restrict__ w, int* __restrict__ cursor,
                               uint2* __restrict__ rec, int n_edges) {
    __shared__ int h[NB];      // hist, then local cursor
    __shared__ int lbase[NB];  // this block's reserved base per bucket
    for (int i = threadIdx.x; i < NB; i += 256) h[i] = 0;
    __syncthreads();
    const int base = blockIdx.x * CHUNK;
    for (int i = threadIdx.x; i < CHUNK; i += 256) {
        int e = base + i;
        if (e < n_edges) atomicAdd(&h[row[e] >> 7], 1);
    }
    __syncthreads();
    for (int i = threadIdx.x; i < NB; i += 256) {
        int c = h[i];
        lbase[i] = c ? atomicAdd(&cursor[i], c) : 0;
    }
    __syncthreads();
    for (int i = threadIdx.x; i < NB; i += 256) h[i] = 0;
    __syncthreads();
    for (int i = threadIdx.x; i < CHUNK; i += 256) {
        int e = base + i;
        if (e < n_edges) {
            int r = row[e];
            int b = r >> 7;
            int pos = lbase[b] + atomicAdd(&h[b], 1);
            unsigned packed = ((unsigned)(r & 127) << 17) | (unsigned)col[e];
            rec[pos] = make_uint2(packed, __float_as_uint(w[e]));
        }
    }
}

// ================= stage 2: per-bucket counting sort -> full CSR =================
// one block per bucket; writes rec2 (col,w) in row-sorted order + row_ptr.
__global__ void bucket_sort(const int* __restrict__ bbase, const uint2* __restrict__ rec,
                            uint2* __restrict__ rec2, int* __restrict__ row_ptr,
                            int n_nodes) {
    __shared__ int hist[RPB];
    __shared__ int scanbuf[RPB];
    __shared__ int lcur[RPB];
    const int t = threadIdx.x;
    const int b = blockIdx.x;
    const int s = bbase[b], e = bbase[b + 1];
    if (t < RPB) hist[t] = 0;
    __syncthreads();
    for (int i = s + t; i < e; i += 256)
        atomicAdd(&hist[rec[i].x >> 17], 1);
    __syncthreads();
    if (t < RPB) scanbuf[t] = hist[t];
    __syncthreads();
    for (int off = 1; off < RPB; off <<= 1) {
        int v = (t < RPB && t >= off) ? scanbuf[t - off] : 0;
        __syncthreads();
        if (t < RPB) scanbuf[t] += v;
        __syncthreads();
    }
    if (t < RPB) {
        int excl = scanbuf[t] - hist[t];
        lcur[t] = excl;
        int gr = b * RPB + t;
        if (gr <= n_nodes) row_ptr[gr] = s + excl;
    }
    __syncthreads();
    for (int i = s + t; i < e; i += 256) {
        uint2 rv = rec[i];
        int r = rv.x >> 17;
        int pos = s + atomicAdd(&lcur[r], 1);
        rec2[pos] = make_uint2(rv.x & 0x1FFFF, rv.y);
    }
}

// ================= SPMM (CSR gather, reg accumulate) + bias + ELU =================
// 8 threads per node, each owns a float4 of the 32 feats; x4 unrolled gathers.
__global__ void spmm_csr(const int* __restrict__ rp, const uint2* __restrict__ rec2,
                         const float* __restrict__ hin, const float* __restrict__ b,
                         float* __restrict__ out, int n_nodes) {
    const int fg = threadIdx.x & 7;
    const int node = blockIdx.x * 32 + (threadIdx.x >> 3);
    if (node >= n_nodes) return;
    const int s = rp[node], e = rp[node + 1];
    const float4* h4 = (const float4*)hin;
    float4 acc = make_float4(0.f, 0.f, 0.f, 0.f);
    int i = s;
    for (; i + 4 <= e; i += 4) {
        uint2 r0 = rec2[i];
        uint2 r1 = rec2[i + 1];
        uint2 r2 = rec2[i + 2];
        uint2 r3 = rec2[i + 3];
        float4 h0 = h4[(size_t)r0.x * 8 + fg];
        float4 h1 = h4[(size_t)r1.x * 8 + fg];
        float4 h2 = h4[(size_t)r2.x * 8 + fg];
        float4 h3 = h4[(size_t)r3.x * 8 + fg];
        float w0 = __uint_as_float(r0.y), w1 = __uint_as_float(r1.y);
        float w2 = __uint_as_float(r2.y), w3 = __uint_as_float(r3.y);
        acc.x += w0 * h0.x + w1 * h1.x + w2 * h2.x + w3 * h3.x;
        acc.y += w0 * h0.y + w1 * h1.y + w2 * h2.y + w3 * h3.y;
        acc.z += w0 * h0.z + w1 * h1.z + w2 * h2.z + w3 * h3.z;
        acc.w += w0 * h0.w + w1 * h1.w + w2 * h2.w + w3 * h3.w;
    }
    for (; i < e; ++i) {
        uint2 r0 = rec2[i];
        float4 h0 = h4[(size_t)r0.x * 8 + fg];
        float w0 = __uint_as_float(r0.y);
        acc.x += w0 * h0.x; acc.y += w0 * h0.y;
        acc.z += w0 * h0.z; acc.w += w0 * h0.w;
    }
    float4 bv = ((const float4*)b)[fg];
    acc.x += bv.x; acc.y += bv.y; acc.z += bv.z; acc.w += bv.w;
    acc.x = acc.x > 0.f ? acc.x : (expf(acc.x) - 1.f);
    acc.y = acc.y > 0.f ? acc.y : (expf(acc.y) - 1.f);
    acc.z = acc.z > 0.f ? acc.z : (expf(acc.z) - 1.f);
    acc.w = acc.w > 0.f ? acc.w : (expf(acc.w) - 1.f);
    ((float4*)(out + (size_t)node * 32))[fg] = acc;
}

// ================= pool: sorted seg run-accumulation =================
__global__ void pool_seg(const float* __restrict__ h, const int* __restrict__ seg,
                         float* __restrict__ g, int n_nodes) {
    const int t = threadIdx.x;
    const int f = t & 31;
    const int sub = t >> 5;
    const int base = blockIdx.x * 512;
    float run = 0.f;
    int cur = -1;
    for (int i = 0; i < 64; ++i) {
        int node = base + sub + i * 8;
        if (node >= n_nodes) break;
        int sg = seg[node];
        if (sg != cur) {
            if (cur >= 0) atomicAdd(&g[(size_t)cur * 32 + f], run);
            cur = sg;
            run = 0.f;
        }
        run += h[(size_t)node * 32 + f];
    }
    if (cur >= 0) atomicAdd(&g[(size_t)cur * 32 + f], run);
}

// ================= MLP head =================
__global__ void head_mlp(const float* __restrict__ g,
                         const float* __restrict__ Wd1, const float* __restrict__ bd1,
                         const float* __restrict__ Wd2, const float* __restrict__ bd2,
                         const float* __restrict__ Wd3, const float* __restrict__ bd3,
                         float* __restrict__ out) {
    __shared__ float gr[32];
    __shared__ float s1[64];
    __shared__ float s2[32];
    const int gid = blockIdx.x;
    const int t = threadIdx.x;
    if (t < 32) gr[t] = g[(size_t)gid * 32 + t];
    __syncthreads();
    float a = bd1[t];
    for (int k = 0; k < 32; ++k) a += gr[k] * Wd1[k * 64 + t];
    s1[t] = fmaxf(a, 0.f);
    __syncthreads();
    if (t < 32) {
        float a2 = bd2[t];
        for (int k = 0; k < 64; ++k) a2 += s1[k] * Wd2[k * 32 + t];
        s2[t] = fmaxf(a2, 0.f);
    }
    __syncthreads();
    if (t == 0) {
        float a3 = bd3[0];
        for (int k = 0; k < 32; ++k) a3 += s2[k] * Wd3[k];
        out[gid] = 1.f / (1.f + expf(-a3));
    }
}

extern "C" void kernel_launch(void* const* d_in, const int* in_sizes, int n_in,
                              void* d_out, int out_size, void* d_ws, size_t ws_size,
                              hipStream_t stream) {
    const float* x   = (const float*)d_in[0];
    const int*   ei  = (const int*)d_in[1];
    const float* ew  = (const float*)d_in[2];
    const int*   seg = (const int*)d_in[3];
    const float* W1  = (const float*)d_in[4];
    const float* b1  = (const float*)d_in[5];
    const float* W2  = (const float*)d_in[6];
    const float* b2  = (const float*)d_in[7];
    const float* W3  = (const float*)d_in[8];
    const float* b3  = (const float*)d_in[9];
    const float* Wd1 = (const float*)d_in[10];
    const float* bd1 = (const float*)d_in[11];
    const float* Wd2 = (const float*)d_in[12];
    const float* bd2 = (const float*)d_in[13];
    const float* Wd3 = (const float*)d_in[14];
    const float* bd3 = (const float*)d_in[15];
    float* out = (float*)d_out;

    const int* rowp = ei;
    const int* colp = ei + N_EDGES;

    const size_t NF = (size_t)N_NODES * F_HID;
    float* B0      = (float*)d_ws;             // projected h
    float* B2      = B0 + NF;                  // activated h
    uint2* rec     = (uint2*)(B2 + NF);        // [E] bucketed (rowlocal|col, w)
    uint2* rec2    = rec + N_EDGES;            // [E] CSR-sorted (col, w)
    int*   cnt     = (int*)(rec2 + N_EDGES);   // [NB]
    int*   bbase   = cnt + NB;                 // [NB+1]
    int*   cursor  = bbase + NB + 1;           // [NB]
    int*   row_ptr = cursor + NB;              // [N+1]
    float* G       = (float*)(row_ptr + N_NODES + 1);  // [512,32]

    const int gemm_grid = (N_NODES + 31) / 32;
    const int pool_grid = (N_NODES + 511) / 512;

    // ---- two-level CSR build (once per call) ----
    hipMemsetAsync(cnt, 0, NB * sizeof(int), stream);
    bucket_hist<<<NCHUNK, 256, 0, stream>>>(rowp, cnt, N_EDGES);
    scan_nb<<<1, 1024, 0, stream>>>(cnt, bbase, cursor);
    bucket_scatter<<<NCHUNK, 256, 0, stream>>>(rowp, colp, ew, cursor, rec, N_EDGES);
    bucket_sort<<<NB, 256, 0, stream>>>(bbase, rec, rec2, row_ptr, N_NODES);

    // ---- layer 1 ----
    gemm128x32<<<gemm_grid, 256, 0, stream>>>(x, W1, B0, N_NODES);
    spmm_csr<<<gemm_grid, 256, 0, stream>>>(row_ptr, rec2, B0, b1, B2, N_NODES);

    // ---- layer 2 ----
    gemm32x32<<<gemm_grid, 256, 0, stream>>>(B2, W2, B0, N_NODES);
    spmm_csr<<<gemm_grid, 256, 0, stream>>>(row_ptr, rec2, B0, b2, B2, N_NODES);

    // ---- layer 3 ----
    gemm32x32<<<gemm_grid, 256, 0, stream>>>(B2, W3, B0, N_NODES);
    spmm_csr<<<gemm_grid, 256, 0, stream>>>(row_ptr, rec2, B0, b3, B2, N_NODES);

    // ---- pool + head ----
    hipMemsetAsync(G, 0, (size_t)N_GRAPHS * F_HID * sizeof(float), stream);
    pool_seg<<<pool_grid, 256, 0, stream>>>(B2, seg, G, N_NODES);
    head_mlp<<<N_GRAPHS, 64, 0, stream>>>(G, Wd1, bd1, Wd2, bd2, Wd3, bd3, out);
}

// Round 5
// 473.505 us; speedup vs baseline: 4.9457x; 1.1078x over previous
//
#include <hip/hip_runtime.h>
#include <math.h>

#define N_NODES 100000
#define N_EDGES 3200000
#define N_GRAPHS 512
#define D_FEAT 128
#define F_HID 32

#define RPB 128                 // rows per bucket (row >> 7)
#define NB 782                  // ceil(100000/128)
#define CAP 5120                // fixed bucket capacity (mean 4092, sigma 64 -> 16 sigma)
#define CHUNK 8192              // edges per multisplit block
#define NCHUNK ((N_EDGES + CHUNK - 1) / CHUNK)   // 391

// ---------------- GEMM1: x[N,128] @ W[128,32] -> out[N,32] ----------------
__global__ void gemm128x32(const float* __restrict__ x, const float* __restrict__ W,
                           float* __restrict__ out, int n_nodes) {
    __shared__ float Ws[128 * 32];
    for (int i = threadIdx.x; i < 128 * 32; i += 256) Ws[i] = W[i];
    __syncthreads();
    const int fg = threadIdx.x & 7;
    const int nl = threadIdx.x >> 3;
    const int node = blockIdx.x * 32 + nl;
    if (node >= n_nodes) return;
    const float4* x4 = (const float4*)(x + (size_t)node * 128);
    const float4* Ws4 = (const float4*)Ws;
    float4 acc = make_float4(0.f, 0.f, 0.f, 0.f);
    for (int kk = 0; kk < 32; ++kk) {
        float4 xv = x4[kk];
        int k = kk * 4;
        float4 w0 = Ws4[(k + 0) * 8 + fg];
        float4 w1 = Ws4[(k + 1) * 8 + fg];
        float4 w2 = Ws4[(k + 2) * 8 + fg];
        float4 w3 = Ws4[(k + 3) * 8 + fg];
        acc.x += xv.x * w0.x + xv.y * w1.x + xv.z * w2.x + xv.w * w3.x;
        acc.y += xv.x * w0.y + xv.y * w1.y + xv.z * w2.y + xv.w * w3.y;
        acc.z += xv.x * w0.z + xv.y * w1.z + xv.z * w2.z + xv.w * w3.z;
        acc.w += xv.x * w0.w + xv.y * w1.w + xv.z * w2.w + xv.w * w3.w;
    }
    ((float4*)(out + (size_t)node * 32))[fg] = acc;
}

// ---------------- GEMM: h[N,32] @ W[32,32] -> out[N,32] ----------------
__global__ void gemm32x32(const float* __restrict__ h, const float* __restrict__ W,
                          float* __restrict__ out, int n_nodes) {
    __shared__ float Ws[32 * 32];
    for (int i = threadIdx.x; i < 32 * 32; i += 256) Ws[i] = W[i];
    __syncthreads();
    const int fg = threadIdx.x & 7;
    const int nl = threadIdx.x >> 3;
    const int node = blockIdx.x * 32 + nl;
    if (node >= n_nodes) return;
    const float4* h4 = (const float4*)(h + (size_t)node * 32);
    const float4* Ws4 = (const float4*)Ws;
    float4 acc = make_float4(0.f, 0.f, 0.f, 0.f);
    for (int kk = 0; kk < 8; ++kk) {
        float4 hv = h4[kk];
        int k = kk * 4;
        float4 w0 = Ws4[(k + 0) * 8 + fg];
        float4 w1 = Ws4[(k + 1) * 8 + fg];
        float4 w2 = Ws4[(k + 2) * 8 + fg];
        float4 w3 = Ws4[(k + 3) * 8 + fg];
        acc.x += hv.x * w0.x + hv.y * w1.x + hv.z * w2.x + hv.w * w3.x;
        acc.y += hv.x * w0.y + hv.y * w1.y + hv.z * w2.y + hv.w * w3.y;
        acc.z += hv.x * w0.z + hv.y * w1.z + hv.z * w2.z + hv.w * w3.z;
        acc.w += hv.x * w0.w + hv.y * w1.w + hv.z * w2.w + hv.w * w3.w;
    }
    ((float4*)(out + (size_t)node * 32))[fg] = acc;
}

// ================= stage 0: cursor init (fixed-capacity buckets) =================
__global__ void init_cursor(int* __restrict__ cursor) {
    int t = blockIdx.x * blockDim.x + threadIdx.x;
    if (t < NB) cursor[t] = t * CAP;
}

// ================= stage 1: bucket multisplit, LDS-staged coalesced writes =======
__global__ __launch_bounds__(256) void bucket_scatter(
        const int* __restrict__ row, const int* __restrict__ col,
        const float* __restrict__ w, int* __restrict__ cursor,
        uint2* __restrict__ rec, int n_edges) {
    __shared__ uint2 srt[CHUNK];      // 64 KB: chunk sorted by bucket
    __shared__ int hist[NB];
    __shared__ int lofs[NB + 1];      // local exclusive offsets
    __shared__ int lbase[NB];         // global reserved base per bucket
    __shared__ int tsum[256];
    const int t = threadIdx.x;
    const int base = blockIdx.x * CHUNK;
    const int count = min(CHUNK, n_edges - base);

    for (int i = t; i < NB; i += 256) hist[i] = 0;
    __syncthreads();
    for (int i = t; i < count; i += 256)
        atomicAdd(&hist[row[base + i] >> 7], 1);
    __syncthreads();

    // two-level exclusive scan of hist[NB] -> lofs
    int vals[4];
    int s0 = 0;
    const int b4 = t * 4;
    #pragma unroll
    for (int j = 0; j < 4; ++j) {
        int idx = b4 + j;
        vals[j] = (idx < NB) ? hist[idx] : 0;
        s0 += vals[j];
    }
    tsum[t] = s0;
    __syncthreads();
    for (int off = 1; off < 256; off <<= 1) {
        int add = (t >= off) ? tsum[t - off] : 0;
        __syncthreads();
        tsum[t] += add;
        __syncthreads();
    }
    int run = tsum[t] - s0;
    #pragma unroll
    for (int j = 0; j < 4; ++j) {
        int idx = b4 + j;
        if (idx < NB) lofs[idx] = run;
        run += vals[j];
    }
    if (t == 255) lofs[NB] = tsum[255];   // == count
    __syncthreads();

    // reserve global ranges; reset hist to use as local cursor
    for (int i = t; i < NB; i += 256) {
        int c = hist[i];
        lbase[i] = c ? atomicAdd(&cursor[i], c) : 0;
        hist[i] = 0;
    }
    __syncthreads();

    // place records into LDS in bucket-sorted order
    for (int i = t; i < count; i += 256) {
        int e = base + i;
        int r = row[e];
        int b = r >> 7;
        int pos = lofs[b] + atomicAdd(&hist[b], 1);
        srt[pos] = make_uint2(((unsigned)(r & 127) << 17) | (unsigned)col[e],
                              __float_as_uint(w[e]));
    }
    __syncthreads();

    // coalesced write-out: consecutive lanes -> consecutive global addresses per run
    for (int i = t; i < count; i += 256) {
        uint2 v = srt[i];
        int lo = 0, hi = NB;              // largest b with lofs[b] <= i
        while (hi - lo > 1) {
            int mid = (lo + hi) >> 1;
            if (lofs[mid] <= i) lo = mid; else hi = mid;
        }
        rec[lbase[lo] + (i - lofs[lo])] = v;
    }
}

// ================= stage 2: compact-base scan over bucket counts =================
__global__ void scan_nb(const int* __restrict__ cursor, int* __restrict__ bbase) {
    __shared__ int s[1024];
    const int t = threadIdx.x;
    int v = (t < NB) ? (cursor[t] - t * CAP) : 0;
    s[t] = v;
    __syncthreads();
    for (int off = 1; off < 1024; off <<= 1) {
        int add = (t >= off) ? s[t - off] : 0;
        __syncthreads();
        s[t] += add;
        __syncthreads();
    }
    if (t < NB) bbase[t] = s[t] - v;
    if (t == NB - 1) bbase[NB] = s[t];
}

// ================= stage 3: per-bucket counting sort -> compact CSR ==============
__global__ __launch_bounds__(256) void bucket_sort(
        const int* __restrict__ cursor, const int* __restrict__ bbase,
        const uint2* __restrict__ rec, uint2* __restrict__ rec2,
        int* __restrict__ row_ptr, int n_nodes) {
    __shared__ uint2 srt[CAP];        // 40 KB
    __shared__ int hist[RPB];
    __shared__ int lofs[RPB];
    const int t = threadIdx.x;
    const int b = blockIdx.x;
    const int sbase = b * CAP;
    const int cnt = cursor[b] - sbase;
    const int gbase = bbase[b];

    if (t < RPB) hist[t] = 0;
    __syncthreads();
    for (int i = t; i < cnt; i += 256)
        atomicAdd(&hist[rec[sbase + i].x >> 17], 1);
    __syncthreads();
    if (t < RPB) lofs[t] = hist[t];
    __syncthreads();
    for (int off = 1; off < RPB; off <<= 1) {
        int v = (t < RPB && t >= off) ? lofs[t - off] : 0;
        __syncthreads();
        if (t < RPB) lofs[t] += v;
        __syncthreads();
    }
    if (t < RPB) {
        int excl = lofs[t] - hist[t];
        int gr = b * RPB + t;
        if (gr <= n_nodes) row_ptr[gr] = gbase + excl;
        hist[t] = excl;               // reuse as placement cursor
    }
    __syncthreads();
    for (int i = t; i < cnt; i += 256) {
        uint2 v = rec[sbase + i];
        int pos = atomicAdd(&hist[v.x >> 17], 1);
        srt[pos] = make_uint2(v.x & 0x1FFFF, v.y);
    }
    __syncthreads();
    // linear coalesced write-out (slab is block-exclusive)
    for (int i = t; i < cnt; i += 256)
        rec2[gbase + i] = srt[i];
}

// ================= SPMM (CSR gather, reg accumulate) + bias + ELU =================
__global__ void spmm_csr(const int* __restrict__ rp, const uint2* __restrict__ rec2,
                         const float* __restrict__ hin, const float* __restrict__ b,
                         float* __restrict__ out, int n_nodes) {
    const int fg = threadIdx.x & 7;
    const int node = blockIdx.x * 32 + (threadIdx.x >> 3);
    if (node >= n_nodes) return;
    const int s = rp[node], e = rp[node + 1];
    const float4* h4 = (const float4*)hin;
    float4 acc = make_float4(0.f, 0.f, 0.f, 0.f);
    int i = s;
    for (; i + 4 <= e; i += 4) {
        uint2 r0 = rec2[i];
        uint2 r1 = rec2[i + 1];
        uint2 r2 = rec2[i + 2];
        uint2 r3 = rec2[i + 3];
        float4 h0 = h4[(size_t)r0.x * 8 + fg];
        float4 h1 = h4[(size_t)r1.x * 8 + fg];
        float4 h2 = h4[(size_t)r2.x * 8 + fg];
        float4 h3 = h4[(size_t)r3.x * 8 + fg];
        float w0 = __uint_as_float(r0.y), w1 = __uint_as_float(r1.y);
        float w2 = __uint_as_float(r2.y), w3 = __uint_as_float(r3.y);
        acc.x += w0 * h0.x + w1 * h1.x + w2 * h2.x + w3 * h3.x;
        acc.y += w0 * h0.y + w1 * h1.y + w2 * h2.y + w3 * h3.y;
        acc.z += w0 * h0.z + w1 * h1.z + w2 * h2.z + w3 * h3.z;
        acc.w += w0 * h0.w + w1 * h1.w + w2 * h2.w + w3 * h3.w;
    }
    for (; i < e; ++i) {
        uint2 r0 = rec2[i];
        float4 h0 = h4[(size_t)r0.x * 8 + fg];
        float w0 = __uint_as_float(r0.y);
        acc.x += w0 * h0.x; acc.y += w0 * h0.y;
        acc.z += w0 * h0.z; acc.w += w0 * h0.w;
    }
    float4 bv = ((const float4*)b)[fg];
    acc.x += bv.x; acc.y += bv.y; acc.z += bv.z; acc.w += bv.w;
    acc.x = acc.x > 0.f ? acc.x : (expf(acc.x) - 1.f);
    acc.y = acc.y > 0.f ? acc.y : (expf(acc.y) - 1.f);
    acc.z = acc.z > 0.f ? acc.z : (expf(acc.z) - 1.f);
    acc.w = acc.w > 0.f ? acc.w : (expf(acc.w) - 1.f);
    ((float4*)(out + (size_t)node * 32))[fg] = acc;
}

// ================= pool: sorted seg run-accumulation =================
__global__ void pool_seg(const float* __restrict__ h, const int* __restrict__ seg,
                         float* __restrict__ g, int n_nodes) {
    const int t = threadIdx.x;
    const int f = t & 31;
    const int sub = t >> 5;
    const int base = blockIdx.x * 512;
    float run = 0.f;
    int cur = -1;
    for (int i = 0; i < 64; ++i) {
        int node = base + sub + i * 8;
        if (node >= n_nodes) break;
        int sg = seg[node];
        if (sg != cur) {
            if (cur >= 0) atomicAdd(&g[(size_t)cur * 32 + f], run);
            cur = sg;
            run = 0.f;
        }
        run += h[(size_t)node * 32 + f];
    }
    if (cur >= 0) atomicAdd(&g[(size_t)cur * 32 + f], run);
}

// ================= MLP head =================
__global__ void head_mlp(const float* __restrict__ g,
                         const float* __restrict__ Wd1, const float* __restrict__ bd1,
                         const float* __restrict__ Wd2, const float* __restrict__ bd2,
                         const float* __restrict__ Wd3, const float* __restrict__ bd3,
                         float* __restrict__ out) {
    __shared__ float gr[32];
    __shared__ float s1[64];
    __shared__ float s2[32];
    const int gid = blockIdx.x;
    const int t = threadIdx.x;
    if (t < 32) gr[t] = g[(size_t)gid * 32 + t];
    __syncthreads();
    float a = bd1[t];
    for (int k = 0; k < 32; ++k) a += gr[k] * Wd1[k * 64 + t];
    s1[t] = fmaxf(a, 0.f);
    __syncthreads();
    if (t < 32) {
        float a2 = bd2[t];
        for (int k = 0; k < 64; ++k) a2 += s1[k] * Wd2[k * 32 + t];
        s2[t] = fmaxf(a2, 0.f);
    }
    __syncthreads();
    if (t == 0) {
        float a3 = bd3[0];
        for (int k = 0; k < 32; ++k) a3 += s2[k] * Wd3[k];
        out[gid] = 1.f / (1.f + expf(-a3));
    }
}

extern "C" void kernel_launch(void* const* d_in, const int* in_sizes, int n_in,
                              void* d_out, int out_size, void* d_ws, size_t ws_size,
                              hipStream_t stream) {
    const float* x   = (const float*)d_in[0];
    const int*   ei  = (const int*)d_in[1];
    const float* ew  = (const float*)d_in[2];
    const int*   seg = (const int*)d_in[3];
    const float* W1  = (const float*)d_in[4];
    const float* b1  = (const float*)d_in[5];
    const float* W2  = (const float*)d_in[6];
    const float* b2  = (const float*)d_in[7];
    const float* W3  = (const float*)d_in[8];
    const float* b3  = (const float*)d_in[9];
    const float* Wd1 = (const float*)d_in[10];
    const float* bd1 = (const float*)d_in[11];
    const float* Wd2 = (const float*)d_in[12];
    const float* bd2 = (const float*)d_in[13];
    const float* Wd3 = (const float*)d_in[14];
    const float* bd3 = (const float*)d_in[15];
    float* out = (float*)d_out;

    const int* rowp = ei;
    const int* colp = ei + N_EDGES;

    const size_t NF = (size_t)N_NODES * F_HID;
    const size_t REC_BYTES = (size_t)NB * CAP * sizeof(uint2);  // 32.03 MB

    // region A: rec during build; B0+B2 (25.6 MB) overlay it during layers
    char*  wsb     = (char*)d_ws;
    uint2* rec     = (uint2*)wsb;
    float* B0      = (float*)wsb;
    float* B2      = B0 + NF;
    uint2* rec2    = (uint2*)(wsb + REC_BYTES);        // [E] CSR-sorted (col, w)
    int*   cursor  = (int*)(rec2 + N_EDGES);           // [NB]
    int*   bbase   = cursor + NB;                      // [NB+1]
    int*   row_ptr = bbase + NB + 1;                   // [N+1]
    float* G       = (float*)(row_ptr + N_NODES + 1);  // [512,32]

    const int gemm_grid = (N_NODES + 31) / 32;
    const int pool_grid = (N_NODES + 511) / 512;

    // ---- CSR build (once per call) ----
    init_cursor<<<(NB + 255) / 256, 256, 0, stream>>>(cursor);
    bucket_scatter<<<NCHUNK, 256, 0, stream>>>(rowp, colp, ew, cursor, rec, N_EDGES);
    scan_nb<<<1, 1024, 0, stream>>>(cursor, bbase);
    bucket_sort<<<NB, 256, 0, stream>>>(cursor, bbase, rec, rec2, row_ptr, N_NODES);

    // ---- layer 1 ----
    gemm128x32<<<gemm_grid, 256, 0, stream>>>(x, W1, B0, N_NODES);
    spmm_csr<<<gemm_grid, 256, 0, stream>>>(row_ptr, rec2, B0, b1, B2, N_NODES);

    // ---- layer 2 ----
    gemm32x32<<<gemm_grid, 256, 0, stream>>>(B2, W2, B0, N_NODES);
    spmm_csr<<<gemm_grid, 256, 0, stream>>>(row_ptr, rec2, B0, b2, B2, N_NODES);

    // ---- layer 3 ----
    gemm32x32<<<gemm_grid, 256, 0, stream>>>(B2, W3, B0, N_NODES);
    spmm_csr<<<gemm_grid, 256, 0, stream>>>(row_ptr, rec2, B0, b3, B2, N_NODES);

    // ---- pool + head ----
    hipMemsetAsync(G, 0, (size_t)N_GRAPHS * F_HID * sizeof(float), stream);
    pool_seg<<<pool_grid, 256, 0, stream>>>(B2, seg, G, N_NODES);
    head_mlp<<<N_GRAPHS, 64, 0, stream>>>(G, Wd1, bd1, Wd2, bd2, Wd3, bd3, out);
}

// Round 6
// 403.521 us; speedup vs baseline: 5.8034x; 1.1734x over previous
//
#include <hip/hip_runtime.h>
#include <math.h>

#define N_NODES 100000
#define N_EDGES 3200000
#define N_GRAPHS 512
#define D_FEAT 128
#define F_HID 32

#define RPB 128                 // rows per bucket (row >> 7)
#define NB 782                  // ceil(100000/128)
#define CAP 5120                // fixed bucket capacity (mean 4092 -> 16 sigma margin)
#define CHUNK 8192              // edges per multisplit block
#define NCHUNK ((N_EDGES + CHUNK - 1) / CHUNK)   // 391

// ---- bf16 helpers (RNE, finite values only) ----
static __device__ __forceinline__ unsigned f2bf(float f) {
    unsigned u = __float_as_uint(f);
    return (u + 0x7FFFu + ((u >> 16) & 1u)) >> 16;
}
static __device__ __forceinline__ unsigned pack_bf2(float a, float b) {
    return (f2bf(b) << 16) | f2bf(a);
}
static __device__ __forceinline__ float bf_lo(unsigned u) { return __uint_as_float(u << 16); }
static __device__ __forceinline__ float bf_hi(unsigned u) { return __uint_as_float(u & 0xFFFF0000u); }

// ---------------- GEMM1: x[N,128] @ W[128,32] -> out bf16 [N,32] ----------------
__global__ void gemm128x32(const float* __restrict__ x, const float* __restrict__ W,
                           unsigned short* __restrict__ outb, int n_nodes) {
    __shared__ float Ws[128 * 32];
    for (int i = threadIdx.x; i < 128 * 32; i += 256) Ws[i] = W[i];
    __syncthreads();
    const int fg = threadIdx.x & 7;
    const int nl = threadIdx.x >> 3;
    const int node = blockIdx.x * 32 + nl;
    if (node >= n_nodes) return;
    const float4* x4 = (const float4*)(x + (size_t)node * 128);
    const float4* Ws4 = (const float4*)Ws;
    float4 acc = make_float4(0.f, 0.f, 0.f, 0.f);
    for (int kk = 0; kk < 32; ++kk) {
        float4 xv = x4[kk];
        int k = kk * 4;
        float4 w0 = Ws4[(k + 0) * 8 + fg];
        float4 w1 = Ws4[(k + 1) * 8 + fg];
        float4 w2 = Ws4[(k + 2) * 8 + fg];
        float4 w3 = Ws4[(k + 3) * 8 + fg];
        acc.x += xv.x * w0.x + xv.y * w1.x + xv.z * w2.x + xv.w * w3.x;
        acc.y += xv.x * w0.y + xv.y * w1.y + xv.z * w2.y + xv.w * w3.y;
        acc.z += xv.x * w0.z + xv.y * w1.z + xv.z * w2.z + xv.w * w3.z;
        acc.w += xv.x * w0.w + xv.y * w1.w + xv.z * w2.w + xv.w * w3.w;
    }
    uint2 o = make_uint2(pack_bf2(acc.x, acc.y), pack_bf2(acc.z, acc.w));
    ((uint2*)(outb + (size_t)node * 32))[fg] = o;
}

// ---------------- GEMM: h[N,32] (fp32) @ W[32,32] -> out bf16 [N,32] ----------------
__global__ void gemm32x32(const float* __restrict__ h, const float* __restrict__ W,
                          unsigned short* __restrict__ outb, int n_nodes) {
    __shared__ float Ws[32 * 32];
    for (int i = threadIdx.x; i < 32 * 32; i += 256) Ws[i] = W[i];
    __syncthreads();
    const int fg = threadIdx.x & 7;
    const int nl = threadIdx.x >> 3;
    const int node = blockIdx.x * 32 + nl;
    if (node >= n_nodes) return;
    const float4* h4 = (const float4*)(h + (size_t)node * 32);
    const float4* Ws4 = (const float4*)Ws;
    float4 acc = make_float4(0.f, 0.f, 0.f, 0.f);
    for (int kk = 0; kk < 8; ++kk) {
        float4 hv = h4[kk];
        int k = kk * 4;
        float4 w0 = Ws4[(k + 0) * 8 + fg];
        float4 w1 = Ws4[(k + 1) * 8 + fg];
        float4 w2 = Ws4[(k + 2) * 8 + fg];
        float4 w3 = Ws4[(k + 3) * 8 + fg];
        acc.x += hv.x * w0.x + hv.y * w1.x + hv.z * w2.x + hv.w * w3.x;
        acc.y += hv.x * w0.y + hv.y * w1.y + hv.z * w2.y + hv.w * w3.y;
        acc.z += hv.x * w0.z + hv.y * w1.z + hv.z * w2.z + hv.w * w3.z;
        acc.w += hv.x * w0.w + hv.y * w1.w + hv.z * w2.w + hv.w * w3.w;
    }
    uint2 o = make_uint2(pack_bf2(acc.x, acc.y), pack_bf2(acc.z, acc.w));
    ((uint2*)(outb + (size_t)node * 32))[fg] = o;
}

// ================= stage 0: cursor init (fixed-capacity buckets) =================
__global__ void init_cursor(int* __restrict__ cursor) {
    int t = blockIdx.x * blockDim.x + threadIdx.x;
    if (t < NB) cursor[t] = t * CAP;
}

// ================= stage 1: bucket multisplit, 1024 threads, LDS-staged ==========
__global__ __launch_bounds__(1024) void bucket_scatter(
        const int* __restrict__ row, const int* __restrict__ col,
        const float* __restrict__ w, int* __restrict__ cursor,
        uint2* __restrict__ rec, int n_edges) {
    __shared__ uint2 srt[CHUNK];      // 64 KB
    __shared__ int hist[NB];
    __shared__ int lofs[NB + 1];
    __shared__ int lbase[NB];
    __shared__ int tsum[1024];
    const int t = threadIdx.x;
    const int base = blockIdx.x * CHUNK;
    const int count = min(CHUNK, n_edges - base);

    if (t < NB) hist[t] = 0;
    __syncthreads();
    int rloc[CHUNK / 1024];           // cache row[] between passes
    #pragma unroll
    for (int j = 0; j < CHUNK / 1024; ++j) {
        int i = t + j * 1024;
        int r = -1;
        if (i < count) { r = row[base + i]; atomicAdd(&hist[r >> 7], 1); }
        rloc[j] = r;
    }
    __syncthreads();
    int v = (t < NB) ? hist[t] : 0;
    tsum[t] = v;
    __syncthreads();
    for (int off = 1; off < 1024; off <<= 1) {
        int add = (t >= off) ? tsum[t - off] : 0;
        __syncthreads();
        tsum[t] += add;
        __syncthreads();
    }
    if (t < NB) lofs[t] = tsum[t] - v;
    if (t == 1023) lofs[NB] = tsum[1023];
    __syncthreads();
    if (t < NB) {
        lbase[t] = v ? atomicAdd(&cursor[t], v) : 0;
        hist[t] = 0;
    }
    __syncthreads();
    #pragma unroll
    for (int j = 0; j < CHUNK / 1024; ++j) {
        int i = t + j * 1024;
        if (i < count) {
            int e = base + i;
            int r = rloc[j];
            int b = r >> 7;
            int pos = lofs[b] + atomicAdd(&hist[b], 1);
            srt[pos] = make_uint2(((unsigned)(r & 127) << 17) | (unsigned)col[e],
                                  __float_as_uint(w[e]));
        }
    }
    __syncthreads();
    // coalesced write-out (runs of ~10 consecutive rec addresses)
    for (int i = t; i < count; i += 1024) {
        uint2 vv = srt[i];
        int lo = 0, hi = NB;
        while (hi - lo > 1) {
            int mid = (lo + hi) >> 1;
            if (lofs[mid] <= i) lo = mid; else hi = mid;
        }
        rec[lbase[lo] + (i - lofs[lo])] = vv;
    }
}

// ================= stage 2: compact-base scan over bucket counts =================
__global__ void scan_nb(const int* __restrict__ cursor, int* __restrict__ bbase) {
    __shared__ int s[1024];
    const int t = threadIdx.x;
    int v = (t < NB) ? (cursor[t] - t * CAP) : 0;
    s[t] = v;
    __syncthreads();
    for (int off = 1; off < 1024; off <<= 1) {
        int add = (t >= off) ? s[t - off] : 0;
        __syncthreads();
        s[t] += add;
        __syncthreads();
    }
    if (t < NB) bbase[t] = s[t] - v;
    if (t == NB - 1) bbase[NB] = s[t];
}

// ================= stage 3: per-bucket counting sort -> compact CSR ==============
__global__ __launch_bounds__(512) void bucket_sort(
        const int* __restrict__ cursor, const int* __restrict__ bbase,
        const uint2* __restrict__ rec, uint2* __restrict__ rec2,
        int* __restrict__ row_ptr, int n_nodes) {
    __shared__ uint2 srt[CAP];        // 40 KB
    __shared__ int hist[RPB];
    __shared__ int lofs[RPB];
    const int t = threadIdx.x;
    const int b = blockIdx.x;
    const int sbase = b * CAP;
    const int cnt = cursor[b] - sbase;
    const int gbase = bbase[b];

    if (t < RPB) hist[t] = 0;
    __syncthreads();
    for (int i = t; i < cnt; i += 512)
        atomicAdd(&hist[rec[sbase + i].x >> 17], 1);
    __syncthreads();
    if (t < RPB) lofs[t] = hist[t];
    __syncthreads();
    for (int off = 1; off < RPB; off <<= 1) {
        int v = (t < RPB && t >= off) ? lofs[t - off] : 0;
        __syncthreads();
        if (t < RPB) lofs[t] += v;
        __syncthreads();
    }
    if (t < RPB) {
        int excl = lofs[t] - hist[t];
        int gr = b * RPB + t;
        if (gr <= n_nodes) row_ptr[gr] = gbase + excl;
        hist[t] = excl;               // reuse as placement cursor
    }
    __syncthreads();
    for (int i = t; i < cnt; i += 512) {
        uint2 v = rec[sbase + i];
        int pos = atomicAdd(&hist[v.x >> 17], 1);
        srt[pos] = make_uint2(v.x & 0x1FFFF, v.y);
    }
    __syncthreads();
    for (int i = t; i < cnt; i += 512)
        rec2[gbase + i] = srt[i];
}

// ============ SPMM (CSR gather from bf16 h) + bias + ELU -> fp32 out ============
__global__ void spmm_csr(const int* __restrict__ rp, const uint2* __restrict__ rec2,
                         const unsigned short* __restrict__ hb, const float* __restrict__ b,
                         float* __restrict__ out, int n_nodes) {
    const int fg = threadIdx.x & 7;
    const int node = blockIdx.x * 32 + (threadIdx.x >> 3);
    if (node >= n_nodes) return;
    const int s = rp[node], e = rp[node + 1];
    const uint2* h2 = (const uint2*)hb;   // 4 bf16 per uint2
    float4 acc = make_float4(0.f, 0.f, 0.f, 0.f);
    int i = s;
    for (; i + 4 <= e; i += 4) {
        uint2 r0 = rec2[i];
        uint2 r1 = rec2[i + 1];
        uint2 r2 = rec2[i + 2];
        uint2 r3 = rec2[i + 3];
        uint2 g0 = h2[(size_t)r0.x * 8 + fg];
        uint2 g1 = h2[(size_t)r1.x * 8 + fg];
        uint2 g2 = h2[(size_t)r2.x * 8 + fg];
        uint2 g3 = h2[(size_t)r3.x * 8 + fg];
        float w0 = __uint_as_float(r0.y), w1 = __uint_as_float(r1.y);
        float w2 = __uint_as_float(r2.y), w3 = __uint_as_float(r3.y);
        acc.x += w0 * bf_lo(g0.x) + w1 * bf_lo(g1.x) + w2 * bf_lo(g2.x) + w3 * bf_lo(g3.x);
        acc.y += w0 * bf_hi(g0.x) + w1 * bf_hi(g1.x) + w2 * bf_hi(g2.x) + w3 * bf_hi(g3.x);
        acc.z += w0 * bf_lo(g0.y) + w1 * bf_lo(g1.y) + w2 * bf_lo(g2.y) + w3 * bf_lo(g3.y);
        acc.w += w0 * bf_hi(g0.y) + w1 * bf_hi(g1.y) + w2 * bf_hi(g2.y) + w3 * bf_hi(g3.y);
    }
    for (; i < e; ++i) {
        uint2 r0 = rec2[i];
        uint2 g0 = h2[(size_t)r0.x * 8 + fg];
        float w0 = __uint_as_float(r0.y);
        acc.x += w0 * bf_lo(g0.x); acc.y += w0 * bf_hi(g0.x);
        acc.z += w0 * bf_lo(g0.y); acc.w += w0 * bf_hi(g0.y);
    }
    float4 bv = ((const float4*)b)[fg];
    acc.x += bv.x; acc.y += bv.y; acc.z += bv.z; acc.w += bv.w;
    acc.x = acc.x > 0.f ? acc.x : (expf(acc.x) - 1.f);
    acc.y = acc.y > 0.f ? acc.y : (expf(acc.y) - 1.f);
    acc.z = acc.z > 0.f ? acc.z : (expf(acc.z) - 1.f);
    acc.w = acc.w > 0.f ? acc.w : (expf(acc.w) - 1.f);
    ((float4*)(out + (size_t)node * 32))[fg] = acc;
}

// ================= pool: sorted seg run-accumulation =================
__global__ void pool_seg(const float* __restrict__ h, const int* __restrict__ seg,
                         float* __restrict__ g, int n_nodes) {
    const int t = threadIdx.x;
    const int f = t & 31;
    const int sub = t >> 5;
    const int base = blockIdx.x * 512;
    float run = 0.f;
    int cur = -1;
    for (int i = 0; i < 64; ++i) {
        int node = base + sub + i * 8;
        if (node >= n_nodes) break;
        int sg = seg[node];
        if (sg != cur) {
            if (cur >= 0) atomicAdd(&g[(size_t)cur * 32 + f], run);
            cur = sg;
            run = 0.f;
        }
        run += h[(size_t)node * 32 + f];
    }
    if (cur >= 0) atomicAdd(&g[(size_t)cur * 32 + f], run);
}

// ================= MLP head =================
__global__ void head_mlp(const float* __restrict__ g,
                         const float* __restrict__ Wd1, const float* __restrict__ bd1,
                         const float* __restrict__ Wd2, const float* __restrict__ bd2,
                         const float* __restrict__ Wd3, const float* __restrict__ bd3,
                         float* __restrict__ out) {
    __shared__ float gr[32];
    __shared__ float s1[64];
    __shared__ float s2[32];
    const int gid = blockIdx.x;
    const int t = threadIdx.x;
    if (t < 32) gr[t] = g[(size_t)gid * 32 + t];
    __syncthreads();
    float a = bd1[t];
    for (int k = 0; k < 32; ++k) a += gr[k] * Wd1[k * 64 + t];
    s1[t] = fmaxf(a, 0.f);
    __syncthreads();
    if (t < 32) {
        float a2 = bd2[t];
        for (int k = 0; k < 64; ++k) a2 += s1[k] * Wd2[k * 32 + t];
        s2[t] = fmaxf(a2, 0.f);
    }
    __syncthreads();
    if (t == 0) {
        float a3 = bd3[0];
        for (int k = 0; k < 32; ++k) a3 += s2[k] * Wd3[k];
        out[gid] = 1.f / (1.f + expf(-a3));
    }
}

extern "C" void kernel_launch(void* const* d_in, const int* in_sizes, int n_in,
                              void* d_out, int out_size, void* d_ws, size_t ws_size,
                              hipStream_t stream) {
    const float* x   = (const float*)d_in[0];
    const int*   ei  = (const int*)d_in[1];
    const float* ew  = (const float*)d_in[2];
    const int*   seg = (const int*)d_in[3];
    const float* W1  = (const float*)d_in[4];
    const float* b1  = (const float*)d_in[5];
    const float* W2  = (const float*)d_in[6];
    const float* b2  = (const float*)d_in[7];
    const float* W3  = (const float*)d_in[8];
    const float* b3  = (const float*)d_in[9];
    const float* Wd1 = (const float*)d_in[10];
    const float* bd1 = (const float*)d_in[11];
    const float* Wd2 = (const float*)d_in[12];
    const float* bd2 = (const float*)d_in[13];
    const float* Wd3 = (const float*)d_in[14];
    const float* bd3 = (const float*)d_in[15];
    float* out = (float*)d_out;

    const int* rowp = ei;
    const int* colp = ei + N_EDGES;

    const size_t NF = (size_t)N_NODES * F_HID;
    const size_t REC_BYTES = (size_t)NB * CAP * sizeof(uint2);  // 32.03 MB

    // region A: rec during build; hb (bf16, 6.4 MB) + B2 (fp32, 12.8 MB) overlay after
    char*  wsb     = (char*)d_ws;
    uint2* rec     = (uint2*)wsb;
    unsigned short* hb = (unsigned short*)wsb;              // bf16 [N,32]
    float* B2      = (float*)(wsb + NF * sizeof(unsigned short));  // fp32 [N,32]
    uint2* rec2    = (uint2*)(wsb + REC_BYTES);             // [E] CSR-sorted (col, w)
    int*   cursor  = (int*)(rec2 + N_EDGES);                // [NB]
    int*   bbase   = cursor + NB;                           // [NB+1]
    int*   row_ptr = bbase + NB + 1;                        // [N+1]
    float* G       = (float*)(row_ptr + N_NODES + 1);       // [512,32]

    const int gemm_grid = (N_NODES + 31) / 32;
    const int pool_grid = (N_NODES + 511) / 512;

    // ---- CSR build (once per call) ----
    init_cursor<<<(NB + 255) / 256, 256, 0, stream>>>(cursor);
    bucket_scatter<<<NCHUNK, 1024, 0, stream>>>(rowp, colp, ew, cursor, rec, N_EDGES);
    scan_nb<<<1, 1024, 0, stream>>>(cursor, bbase);
    bucket_sort<<<NB, 512, 0, stream>>>(cursor, bbase, rec, rec2, row_ptr, N_NODES);

    // ---- layer 1 ----
    gemm128x32<<<gemm_grid, 256, 0, stream>>>(x, W1, hb, N_NODES);
    spmm_csr<<<gemm_grid, 256, 0, stream>>>(row_ptr, rec2, hb, b1, B2, N_NODES);

    // ---- layer 2 ----
    gemm32x32<<<gemm_grid, 256, 0, stream>>>(B2, W2, hb, N_NODES);
    spmm_csr<<<gemm_grid, 256, 0, stream>>>(row_ptr, rec2, hb, b2, B2, N_NODES);

    // ---- layer 3 ----
    gemm32x32<<<gemm_grid, 256, 0, stream>>>(B2, W3, hb, N_NODES);
    spmm_csr<<<gemm_grid, 256, 0, stream>>>(row_ptr, rec2, hb, b3, B2, N_NODES);

    // ---- pool + head ----
    hipMemsetAsync(G, 0, (size_t)N_GRAPHS * F_HID * sizeof(float), stream);
    pool_seg<<<pool_grid, 256, 0, stream>>>(B2, seg, G, N_NODES);
    head_mlp<<<N_GRAPHS, 64, 0, stream>>>(G, Wd1, bd1, Wd2, bd2, Wd3, bd3, out);
}